// Round 8
// baseline (332.822 us; speedup 1.0000x reference)
//
#include <hip/hip_runtime.h>
#include <hip/hip_cooperative_groups.h>
#include <math.h>

#define F        256      // F_IN == F_OUT
#define NGRAPH   512
#define BLOCK    1024
#define NB       512      // phase-A blocks (== grid)
#define NWAVES   (BLOCK / 64)
#define NSLOT    8        // partial slots per graph (graph spans <= 8 chunks)
#define PART_FLOATS (NGRAPH * NSLOT * 257)
#define GCAP     3072     // fallback kernel only

typedef float f32x4 __attribute__((ext_vector_type(4)));

// Wave-cooperative lower_bound: first i with batch[i] >= v.
__device__ __forceinline__ int wave_lb(const int* __restrict__ batch, int n, int v, int lane) {
    int lo = 0, hi = n;
    while (hi - lo > 64) {
        const int step = (hi - lo) >> 6;
        const int q    = lo + (lane + 1) * step;
        const bool c   = (q >= hi) ? true : (batch[q] >= v);
        const unsigned long long m = __ballot(c);
        if (m == 0ull) {
            lo = lo + (step << 6) + 1;
        } else {
            const int l0 = __ffsll((long long)m) - 1;
            const int qh = lo + (l0 + 1) * step;
            const int nlo = (l0 == 0) ? lo : (lo + l0 * step + 1);
            hi = qh < hi ? qh : hi;
            lo = nlo;
        }
    }
    const int q  = lo + lane;
    const bool c = (q < hi) && (batch[q] >= v);
    const unsigned long long m = __ballot(c);
    return (m == 0ull) ? hi : (lo + __ffsll((long long)m) - 1);
}

// ---------------- Cooperative balanced kernel ----------------
// Phase A: equal node chunks -> per-graph partials (no atomics).
// Phase B: 128 blocks x 4 graphs -> normalize + tiled GEMM + gate scale.
__global__ __launch_bounds__(BLOCK, 8) void gap_coop(
        const float* __restrict__ x,
        const float* __restrict__ Wg,
        const float* __restrict__ bg,
        const float* __restrict__ Wnn,
        const float* __restrict__ bnn,
        const int* __restrict__ batch, int n_nodes, int chunk,
        float* __restrict__ out,
        float* __restrict__ gate,
        float* __restrict__ part) {
    __shared__ int bpos[513];
    __shared__ int bgr[513];
    __shared__ int wcnt[NWAVES + 1];
    __shared__ __align__(16) float wacc[NWAVES][F];
    __shared__ float wd[NWAVES];
    __shared__ int sb[5];
    __shared__ float linv[4];
    __shared__ int cntg[4];
    __shared__ __align__(16) f32x4 xbt[F];
    __shared__ float pacc[4][4][F];

    const int b    = blockIdx.x;
    const int tid  = threadIdx.x;
    const int wid  = tid >> 6;
    const int lane = tid & 63;

    const f32x4 wg  = reinterpret_cast<const f32x4*>(Wg)[lane];
    const float bgv = bg[0];

    // ---------------- Phase A ----------------
    const int c0 = b * chunk;
    const int c1 = min(n_nodes, c0 + chunk);
    const int clen = (c1 > c0) ? (c1 - c0) : 0;

    // Boundary detection: segment starts (first row of each graph-run in chunk).
    int nbase = 0;
    for (int t0 = 0; t0 < clen; t0 += BLOCK) {
        const int t = t0 + tid;
        const int i = c0 + t;
        bool flag = false;
        int bv = 0;
        if (t < clen) {
            bv = batch[i];
            flag = (t == 0) || (batch[i - 1] != bv);
        }
        const unsigned long long m = __ballot(flag);
        const int rw = __popcll(m & ((1ull << lane) - 1ull));
        if (lane == 0) wcnt[wid] = __popcll(m);
        __syncthreads();
        if (tid == 0) {
            int acc = nbase;
            #pragma unroll
            for (int w = 0; w < NWAVES; ++w) { const int c = wcnt[w]; wcnt[w] = acc; acc += c; }
            wcnt[NWAVES] = acc;
        }
        __syncthreads();
        if (flag) { const int r = wcnt[wid] + rw; bpos[r] = i; bgr[r] = bv; }
        __syncthreads();
        nbase = wcnt[NWAVES];
        __syncthreads();
    }
    const int nseg = nbase;

    // Per-segment: R6 streaming body, partials -> part[].
    for (int k = 0; k < nseg; ++k) {
        const int s_lo = bpos[k];
        const int s_hi = (k + 1 < nseg) ? bpos[k + 1] : c1;
        const int g    = bgr[k];

        float d = 0.f, ax = 0.f, ay = 0.f, az = 0.f, aw = 0.f;
        int n = s_lo + (wid << 2);
        for (; n + 3 < s_hi; n += 4 * NWAVES) {
            const f32x4* rp = reinterpret_cast<const f32x4*>(x + (size_t)n * F) + lane;
            const f32x4 x0 = __builtin_nontemporal_load(rp);
            const f32x4 x1 = __builtin_nontemporal_load(rp + 64);
            const f32x4 x2 = __builtin_nontemporal_load(rp + 128);
            const f32x4 x3 = __builtin_nontemporal_load(rp + 192);

            float p0 = x0.x * wg.x + x0.y * wg.y + x0.z * wg.z + x0.w * wg.w;
            float p1 = x1.x * wg.x + x1.y * wg.y + x1.z * wg.z + x1.w * wg.w;
            float p2 = x2.x * wg.x + x2.y * wg.y + x2.z * wg.z + x2.w * wg.w;
            float p3 = x3.x * wg.x + x3.y * wg.y + x3.z * wg.z + x3.w * wg.w;
            #pragma unroll
            for (int o = 32; o > 0; o >>= 1) {
                p0 += __shfl_xor(p0, o);
                p1 += __shfl_xor(p1, o);
                p2 += __shfl_xor(p2, o);
                p3 += __shfl_xor(p3, o);
            }
            const float e0 = __expf(p0 + bgv);
            const float e1 = __expf(p1 + bgv);
            const float e2 = __expf(p2 + bgv);
            const float e3 = __expf(p3 + bgv);

            if (lane == 0) {           // unnormalized; phase B rescales
                gate[n]     = e0;
                gate[n + 1] = e1;
                gate[n + 2] = e2;
                gate[n + 3] = e3;
            }
            d += (e0 + e1) + (e2 + e3);
            ax += e0 * x0.x + e1 * x1.x + e2 * x2.x + e3 * x3.x;
            ay += e0 * x0.y + e1 * x1.y + e2 * x2.y + e3 * x3.y;
            az += e0 * x0.z + e1 * x1.z + e2 * x2.z + e3 * x3.z;
            aw += e0 * x0.w + e1 * x1.w + e2 * x2.w + e3 * x3.w;
        }
        for (int t = n; t < s_hi && t < n + 4; ++t) {
            const f32x4 xv = *(reinterpret_cast<const f32x4*>(x + (size_t)t * F) + lane);
            float p = xv.x * wg.x + xv.y * wg.y + xv.z * wg.z + xv.w * wg.w;
            #pragma unroll
            for (int o = 32; o > 0; o >>= 1) p += __shfl_xor(p, o);
            const float e = __expf(p + bgv);
            if (lane == 0) gate[t] = e;
            d += e;
            ax += e * xv.x; ay += e * xv.y; az += e * xv.z; aw += e * xv.w;
        }

        if (lane == 0) wd[wid] = d;
        f32x4 av = {ax, ay, az, aw};
        reinterpret_cast<f32x4*>(&wacc[wid][0])[lane] = av;
        __syncthreads();

        const int slot = (g * NSLOT + (b & (NSLOT - 1))) * 257;
        if (tid < F) {
            float v = 0.f;
            #pragma unroll
            for (int w = 0; w < NWAVES; ++w) v += wacc[w][tid];
            part[slot + tid] = v;
        }
        if (tid == 0) {
            float D = 0.f;
            #pragma unroll
            for (int w = 0; w < NWAVES; ++w) D += wd[w];
            part[slot + 256] = D;
        }
        __syncthreads();
    }

    __threadfence();
    cooperative_groups::this_grid().sync();

    // ---------------- Phase B: 128 blocks x 4 graphs ----------------
    if (b >= NGRAPH / 4) return;
    const int s0 = b << 2;

    if (wid < 5) {
        const int r = wave_lb(batch, n_nodes, s0 + wid, lane);
        if (lane == 0) sb[wid] = r;
    }
    __syncthreads();

    if (tid < 4) {
        const int lo = sb[tid], hi = sb[tid + 1];
        cntg[tid] = hi - lo;
        float D = 0.f;
        if (hi > lo) {
            const int bl = lo / chunk, bh = (hi - 1) / chunk;
            for (int b2 = bl; b2 <= bh; ++b2)
                D += part[((s0 + tid) * NSLOT + (b2 & (NSLOT - 1))) * 257 + 256];
        }
        linv[tid] = 1.f / (D + 1e-16f);
    }
    __syncthreads();

    if (tid < F) {
        float ag[4] = {0.f, 0.f, 0.f, 0.f};
        #pragma unroll
        for (int g = 0; g < 4; ++g) {
            if (cntg[g] > 0) {
                const int lo = sb[g], hi = sb[g + 1];
                const int bl = lo / chunk, bh = (hi - 1) / chunk;
                for (int b2 = bl; b2 <= bh; ++b2)
                    ag[g] += part[((s0 + g) * NSLOT + (b2 & (NSLOT - 1))) * 257 + tid];
                ag[g] *= linv[g];
            }
        }
        f32x4 v = {ag[0], ag[1], ag[2], ag[3]};
        xbt[tid] = v;
    }
    __syncthreads();

    // Tiled GEMM: 4 graphs share each Wnn element. thread (q, j), k in q-quarter.
    {
        const int q  = tid >> 8;
        const int j  = tid & 255;
        const int k0 = q << 6;
        float t0 = 0.f, t1 = 0.f, t2 = 0.f, t3 = 0.f;
        #pragma unroll 8
        for (int k = k0; k < k0 + 64; ++k) {
            const float wv = Wnn[k * F + j];
            const f32x4 xv = xbt[k];
            t0 += xv.x * wv; t1 += xv.y * wv; t2 += xv.z * wv; t3 += xv.w * wv;
        }
        pacc[q][0][j] = t0; pacc[q][1][j] = t1; pacc[q][2][j] = t2; pacc[q][3][j] = t3;
    }
    __syncthreads();
    {
        const int g2 = tid >> 8;
        const int j2 = tid & 255;
        const float val = pacc[0][g2][j2] + pacc[1][g2][j2] +
                          pacc[2][g2][j2] + pacc[3][g2][j2] + bnn[j2];
        out[(size_t)(s0 + g2) * F + j2] = (cntg[g2] > 0) ? val : 0.f;
    }
    // Scale gate in place for rows of these 4 graphs.
    for (int i = sb[0] + tid; i < sb[4]; i += BLOCK) {
        gate[i] *= linv[batch[i] - s0];
    }
}

// ---------------- Fallback: R6 monolithic kernel (proven 42.65 us) ----------------
__global__ void gap_fused(const float* __restrict__ x,
                          const float* __restrict__ Wg,
                          const float* __restrict__ bg,
                          const float* __restrict__ Wnn,
                          const float* __restrict__ bnn,
                          const int* __restrict__ batch, int n_nodes,
                          float* __restrict__ out,
                          float* __restrict__ gate_out) {
    __shared__ int sbounds[2];
    __shared__ float glds[GCAP];
    __shared__ __align__(16) float wacc[NWAVES][F];
    __shared__ float wd[NWAVES];
    __shared__ float xbar[F];
    __shared__ float partial[BLOCK];

    const int s    = blockIdx.x;
    const int tid  = threadIdx.x;
    const int wid  = tid >> 6;
    const int lane = tid & 63;

    if (wid < 2) {
        const int r = wave_lb(batch, n_nodes, s + wid, lane);
        if (lane == 0) sbounds[wid] = r;
    }
    __syncthreads();
    const int lo  = sbounds[0];
    const int hi  = sbounds[1];
    const int cnt = hi - lo;

    const f32x4 wg  = reinterpret_cast<const f32x4*>(Wg)[lane];
    const float bgv = bg[0];

    float d = 0.f;
    float ax = 0.f, ay = 0.f, az = 0.f, aw = 0.f;

    int n = lo + (wid << 2);
    for (; n + 3 < hi; n += 4 * NWAVES) {
        const f32x4* rp = reinterpret_cast<const f32x4*>(x + (size_t)n * F) + lane;
        const f32x4 x0 = __builtin_nontemporal_load(rp);
        const f32x4 x1 = __builtin_nontemporal_load(rp + 64);
        const f32x4 x2 = __builtin_nontemporal_load(rp + 128);
        const f32x4 x3 = __builtin_nontemporal_load(rp + 192);

        float p0 = x0.x * wg.x + x0.y * wg.y + x0.z * wg.z + x0.w * wg.w;
        float p1 = x1.x * wg.x + x1.y * wg.y + x1.z * wg.z + x1.w * wg.w;
        float p2 = x2.x * wg.x + x2.y * wg.y + x2.z * wg.z + x2.w * wg.w;
        float p3 = x3.x * wg.x + x3.y * wg.y + x3.z * wg.z + x3.w * wg.w;
        #pragma unroll
        for (int o = 32; o > 0; o >>= 1) {
            p0 += __shfl_xor(p0, o);
            p1 += __shfl_xor(p1, o);
            p2 += __shfl_xor(p2, o);
            p3 += __shfl_xor(p3, o);
        }
        const float e0 = __expf(p0 + bgv);
        const float e1 = __expf(p1 + bgv);
        const float e2 = __expf(p2 + bgv);
        const float e3 = __expf(p3 + bgv);

        const int idx = n - lo;
        if (lane == 0 && idx + 3 < GCAP) {
            glds[idx]     = e0;
            glds[idx + 1] = e1;
            glds[idx + 2] = e2;
            glds[idx + 3] = e3;
        }
        d += (e0 + e1) + (e2 + e3);
        ax += e0 * x0.x + e1 * x1.x + e2 * x2.x + e3 * x3.x;
        ay += e0 * x0.y + e1 * x1.y + e2 * x2.y + e3 * x3.y;
        az += e0 * x0.z + e1 * x1.z + e2 * x2.z + e3 * x3.z;
        aw += e0 * x0.w + e1 * x1.w + e2 * x2.w + e3 * x3.w;
    }
    for (int t = n; t < hi && t < n + 4; ++t) {
        const f32x4 xv = *(reinterpret_cast<const f32x4*>(x + (size_t)t * F) + lane);
        float p = xv.x * wg.x + xv.y * wg.y + xv.z * wg.z + xv.w * wg.w;
        #pragma unroll
        for (int o = 32; o > 0; o >>= 1) p += __shfl_xor(p, o);
        const float e = __expf(p + bgv);
        if (lane == 0 && (t - lo) < GCAP) glds[t - lo] = e;
        d += e;
        ax += e * xv.x; ay += e * xv.y; az += e * xv.z; aw += e * xv.w;
    }

    if (lane == 0) wd[wid] = d;
    f32x4 av = {ax, ay, az, aw};
    reinterpret_cast<f32x4*>(&wacc[wid][0])[lane] = av;
    __syncthreads();

    if (cnt > 0) {
        float D = 0.f;
        #pragma unroll
        for (int w = 0; w < NWAVES; ++w) D += wd[w];
        const float inv = 1.f / (D + 1e-16f);

        if (tid < F) {
            float v = 0.f;
            #pragma unroll
            for (int w = 0; w < NWAVES; ++w) v += wacc[w][tid];
            xbar[tid] = v * inv;
        }

        const int nl = cnt < GCAP ? cnt : GCAP;
        for (int idx = tid; idx < nl; idx += BLOCK) {
            gate_out[lo + idx] = glds[idx] * inv;
        }
        for (int t = lo + GCAP + wid; t < hi; t += NWAVES) {
            const f32x4 xv = *(reinterpret_cast<const f32x4*>(x + (size_t)t * F) + lane);
            float p = xv.x * wg.x + xv.y * wg.y + xv.z * wg.z + xv.w * wg.w;
            #pragma unroll
            for (int o = 32; o > 0; o >>= 1) p += __shfl_xor(p, o);
            if (lane == 0) gate_out[t] = __expf(p + bgv) * inv;
        }
        __syncthreads();

        const int q  = tid >> 8;
        const int j  = tid & 255;
        const int k0 = q * 64;
        float sum = 0.f;
        #pragma unroll 8
        for (int k = k0; k < k0 + 64; ++k) sum += xbar[k] * Wnn[k * F + j];
        partial[tid] = sum;
        __syncthreads();
        if (tid < F) {
            out[(size_t)s * F + tid] = partial[tid] + partial[F + tid] +
                                       partial[2 * F + tid] + partial[3 * F + tid] + bnn[tid];
        }
    } else {
        if (tid < F) out[(size_t)s * F + tid] = 0.f;
    }
}

extern "C" void kernel_launch(void* const* d_in, const int* in_sizes, int n_in,
                              void* d_out, int out_size, void* d_ws, size_t ws_size,
                              hipStream_t stream) {
    const float* x     = (const float*)d_in[0];
    const int*   batch = (const int*)d_in[1];
    const float* Wg    = (const float*)d_in[3];
    const float* bg    = (const float*)d_in[4];
    const float* Wnn   = (const float*)d_in[5];
    const float* bnn   = (const float*)d_in[6];

    float* out  = (float*)d_out;                 // [NGRAPH, F]
    float* gate = out + (size_t)NGRAPH * F;      // [N, 1]
    float* part = (float*)d_ws;

    const int N = in_sizes[0] / F;
    const int chunk = (N + NB - 1) / NB;

    if (ws_size >= (size_t)PART_FLOATS * sizeof(float) && chunk <= BLOCK) {
        void* args[] = {(void*)&x, (void*)&Wg, (void*)&bg, (void*)&Wnn, (void*)&bnn,
                        (void*)&batch, (void*)&N, (void*)&chunk,
                        (void*)&out, (void*)&gate, (void*)&part};
        const hipError_t e = hipLaunchCooperativeKernel(gap_coop, dim3(NB), dim3(BLOCK),
                                                        args, 0u, stream);
        if (e == hipSuccess) return;
        (void)hipGetLastError();   // clear, fall through to monolithic path
    }
    gap_fused<<<NGRAPH, BLOCK, 0, stream>>>(x, Wg, bg, Wnn, bnn, batch, N, out, gate);
}

// Round 9
// 166.824 us; speedup vs baseline: 1.9951x; 1.9951x over previous
//
#include <hip/hip_runtime.h>
#include <hip/hip_cooperative_groups.h>
#include <math.h>

#define F        256      // F_IN == F_OUT
#define NGRAPH   512
#define BLOCK    1024
#define NB       256      // coop blocks: exactly 1 per CU
#define NWAVES   (BLOCK / 64)
#define NSLOT    8        // partial slots per graph (graph spans <= 2 chunks here)
#define PART_FLOATS (NGRAPH * NSLOT * 257)
#define GCAP     3072     // fallback kernel only

typedef float f32x4 __attribute__((ext_vector_type(4)));

// Wave-cooperative lower_bound: first i with batch[i] >= v.
__device__ __forceinline__ int wave_lb(const int* __restrict__ batch, int n, int v, int lane) {
    int lo = 0, hi = n;
    while (hi - lo > 64) {
        const int step = (hi - lo) >> 6;
        const int q    = lo + (lane + 1) * step;
        const bool c   = (q >= hi) ? true : (batch[q] >= v);
        const unsigned long long m = __ballot(c);
        if (m == 0ull) {
            lo = lo + (step << 6) + 1;
        } else {
            const int l0 = __ffsll((long long)m) - 1;
            const int qh = lo + (l0 + 1) * step;
            const int nlo = (l0 == 0) ? lo : (lo + l0 * step + 1);
            hi = qh < hi ? qh : hi;
            lo = nlo;
        }
    }
    const int q  = lo + lane;
    const bool c = (q < hi) && (batch[q] >= v);
    const unsigned long long m = __ballot(c);
    return (m == 0ull) ? hi : (lo + __ffsll((long long)m) - 1);
}

// ---------------- Cooperative balanced kernel ----------------
// Phase A: 256 equal node chunks -> per-graph partials (no atomics).
// Phase B: 128 blocks x 4 graphs -> normalize + tiled GEMM + gate scale.
// __launch_bounds__(1024, 4): 4 waves/EU -> VGPR cap 128, no spills (R8's
// (1024,8) throttled to 32 VGPRs and scratch-thrashed at 300 GB/s).
__global__ __launch_bounds__(BLOCK, 4) void gap_coop(
        const float* __restrict__ x,
        const float* __restrict__ Wg,
        const float* __restrict__ bg,
        const float* __restrict__ Wnn,
        const float* __restrict__ bnn,
        const int* __restrict__ batch, int n_nodes, int chunk,
        float* __restrict__ out,
        float* __restrict__ gate,
        float* __restrict__ part) {
    __shared__ int bpos[513];
    __shared__ int bgr[513];
    __shared__ int wcnt[NWAVES + 1];
    __shared__ __align__(16) float wacc[NWAVES][F];
    __shared__ float wd[NWAVES];
    __shared__ int sb[5];
    __shared__ float linv[4];
    __shared__ int cntg[4];
    __shared__ __align__(16) f32x4 xbt[F];
    __shared__ float pacc[4][4][F];

    const int b    = blockIdx.x;
    const int tid  = threadIdx.x;
    const int wid  = tid >> 6;
    const int lane = tid & 63;

    const f32x4 wg  = reinterpret_cast<const f32x4*>(Wg)[lane];
    const float bgv = bg[0];

    // ---------------- Phase A ----------------
    const int c0 = b * chunk;
    const int c1 = min(n_nodes, c0 + chunk);
    const int clen = (c1 > c0) ? (c1 - c0) : 0;

    // Boundary detection: segment starts (first row of each graph-run in chunk).
    int nbase = 0;
    for (int t0 = 0; t0 < clen; t0 += BLOCK) {
        const int t = t0 + tid;
        const int i = c0 + t;
        bool flag = false;
        int bv = 0;
        if (t < clen) {
            bv = batch[i];
            flag = (t == 0) || (batch[i - 1] != bv);
        }
        const unsigned long long m = __ballot(flag);
        const int rw = __popcll(m & ((1ull << lane) - 1ull));
        if (lane == 0) wcnt[wid] = __popcll(m);
        __syncthreads();
        if (tid == 0) {
            int acc = nbase;
            #pragma unroll
            for (int w = 0; w < NWAVES; ++w) { const int c = wcnt[w]; wcnt[w] = acc; acc += c; }
            wcnt[NWAVES] = acc;
        }
        __syncthreads();
        if (flag) { const int r = wcnt[wid] + rw; bpos[r] = i; bgr[r] = bv; }
        __syncthreads();
        nbase = wcnt[NWAVES];
        __syncthreads();
    }
    const int nseg = nbase;

    // Per-segment: R6 streaming body, partials -> part[].
    for (int k = 0; k < nseg; ++k) {
        const int s_lo = bpos[k];
        const int s_hi = (k + 1 < nseg) ? bpos[k + 1] : c1;
        const int g    = bgr[k];

        float d = 0.f, ax = 0.f, ay = 0.f, az = 0.f, aw = 0.f;
        int n = s_lo + (wid << 2);
        for (; n + 3 < s_hi; n += 4 * NWAVES) {
            const f32x4* rp = reinterpret_cast<const f32x4*>(x + (size_t)n * F) + lane;
            const f32x4 x0 = __builtin_nontemporal_load(rp);
            const f32x4 x1 = __builtin_nontemporal_load(rp + 64);
            const f32x4 x2 = __builtin_nontemporal_load(rp + 128);
            const f32x4 x3 = __builtin_nontemporal_load(rp + 192);

            float p0 = x0.x * wg.x + x0.y * wg.y + x0.z * wg.z + x0.w * wg.w;
            float p1 = x1.x * wg.x + x1.y * wg.y + x1.z * wg.z + x1.w * wg.w;
            float p2 = x2.x * wg.x + x2.y * wg.y + x2.z * wg.z + x2.w * wg.w;
            float p3 = x3.x * wg.x + x3.y * wg.y + x3.z * wg.z + x3.w * wg.w;
            #pragma unroll
            for (int o = 32; o > 0; o >>= 1) {
                p0 += __shfl_xor(p0, o);
                p1 += __shfl_xor(p1, o);
                p2 += __shfl_xor(p2, o);
                p3 += __shfl_xor(p3, o);
            }
            const float e0 = __expf(p0 + bgv);
            const float e1 = __expf(p1 + bgv);
            const float e2 = __expf(p2 + bgv);
            const float e3 = __expf(p3 + bgv);

            if (lane == 0) {           // unnormalized; phase B rescales
                gate[n]     = e0;
                gate[n + 1] = e1;
                gate[n + 2] = e2;
                gate[n + 3] = e3;
            }
            d += (e0 + e1) + (e2 + e3);
            ax += e0 * x0.x + e1 * x1.x + e2 * x2.x + e3 * x3.x;
            ay += e0 * x0.y + e1 * x1.y + e2 * x2.y + e3 * x3.y;
            az += e0 * x0.z + e1 * x1.z + e2 * x2.z + e3 * x3.z;
            aw += e0 * x0.w + e1 * x1.w + e2 * x2.w + e3 * x3.w;
        }
        for (int t = n; t < s_hi && t < n + 4; ++t) {
            const f32x4 xv = *(reinterpret_cast<const f32x4*>(x + (size_t)t * F) + lane);
            float p = xv.x * wg.x + xv.y * wg.y + xv.z * wg.z + xv.w * wg.w;
            #pragma unroll
            for (int o = 32; o > 0; o >>= 1) p += __shfl_xor(p, o);
            const float e = __expf(p + bgv);
            if (lane == 0) gate[t] = e;
            d += e;
            ax += e * xv.x; ay += e * xv.y; az += e * xv.z; aw += e * xv.w;
        }

        if (lane == 0) wd[wid] = d;
        f32x4 av = {ax, ay, az, aw};
        reinterpret_cast<f32x4*>(&wacc[wid][0])[lane] = av;
        __syncthreads();

        const int slot = (g * NSLOT + (b & (NSLOT - 1))) * 257;
        if (tid < F) {
            float v = 0.f;
            #pragma unroll
            for (int w = 0; w < NWAVES; ++w) v += wacc[w][tid];
            part[slot + tid] = v;
        }
        if (tid == 0) {
            float D = 0.f;
            #pragma unroll
            for (int w = 0; w < NWAVES; ++w) D += wd[w];
            part[slot + 256] = D;
        }
        __syncthreads();
    }

    __threadfence();
    cooperative_groups::this_grid().sync();

    // ---------------- Phase B: 128 blocks x 4 graphs ----------------
    if (b >= NGRAPH / 4) return;
    const int s0 = b << 2;

    if (wid < 5) {
        const int r = wave_lb(batch, n_nodes, s0 + wid, lane);
        if (lane == 0) sb[wid] = r;
    }
    __syncthreads();

    if (tid < 4) {
        const int lo = sb[tid], hi = sb[tid + 1];
        cntg[tid] = hi - lo;
        float D = 0.f;
        if (hi > lo) {
            const int bl = lo / chunk, bh = (hi - 1) / chunk;
            for (int b2 = bl; b2 <= bh; ++b2)
                D += part[((s0 + tid) * NSLOT + (b2 & (NSLOT - 1))) * 257 + 256];
        }
        linv[tid] = 1.f / (D + 1e-16f);
    }
    __syncthreads();

    if (tid < F) {
        float ag[4] = {0.f, 0.f, 0.f, 0.f};
        #pragma unroll
        for (int g = 0; g < 4; ++g) {
            if (cntg[g] > 0) {
                const int lo = sb[g], hi = sb[g + 1];
                const int bl = lo / chunk, bh = (hi - 1) / chunk;
                for (int b2 = bl; b2 <= bh; ++b2)
                    ag[g] += part[((s0 + g) * NSLOT + (b2 & (NSLOT - 1))) * 257 + tid];
                ag[g] *= linv[g];
            }
        }
        f32x4 v = {ag[0], ag[1], ag[2], ag[3]};
        xbt[tid] = v;
    }
    __syncthreads();

    // Tiled GEMM: 4 graphs share each Wnn element. thread (q, j), k in q-quarter.
    {
        const int q  = tid >> 8;
        const int j  = tid & 255;
        const int k0 = q << 6;
        float t0 = 0.f, t1 = 0.f, t2 = 0.f, t3 = 0.f;
        #pragma unroll 8
        for (int k = k0; k < k0 + 64; ++k) {
            const float wv = Wnn[k * F + j];
            const f32x4 xv = xbt[k];
            t0 += xv.x * wv; t1 += xv.y * wv; t2 += xv.z * wv; t3 += xv.w * wv;
        }
        pacc[q][0][j] = t0; pacc[q][1][j] = t1; pacc[q][2][j] = t2; pacc[q][3][j] = t3;
    }
    __syncthreads();
    {
        const int g2 = tid >> 8;
        const int j2 = tid & 255;
        const float val = pacc[0][g2][j2] + pacc[1][g2][j2] +
                          pacc[2][g2][j2] + pacc[3][g2][j2] + bnn[j2];
        out[(size_t)(s0 + g2) * F + j2] = (cntg[g2] > 0) ? val : 0.f;
    }
    // Scale gate in place for rows of these 4 graphs.
    for (int i = sb[0] + tid; i < sb[4]; i += BLOCK) {
        gate[i] *= linv[batch[i] - s0];
    }
}

// ---------------- Fallback: R6 monolithic kernel (proven 42.65 us) ----------------
__global__ void gap_fused(const float* __restrict__ x,
                          const float* __restrict__ Wg,
                          const float* __restrict__ bg,
                          const float* __restrict__ Wnn,
                          const float* __restrict__ bnn,
                          const int* __restrict__ batch, int n_nodes,
                          float* __restrict__ out,
                          float* __restrict__ gate_out) {
    __shared__ int sbounds[2];
    __shared__ float glds[GCAP];
    __shared__ __align__(16) float wacc[NWAVES][F];
    __shared__ float wd[NWAVES];
    __shared__ float xbar[F];
    __shared__ float partial[BLOCK];

    const int s    = blockIdx.x;
    const int tid  = threadIdx.x;
    const int wid  = tid >> 6;
    const int lane = tid & 63;

    if (wid < 2) {
        const int r = wave_lb(batch, n_nodes, s + wid, lane);
        if (lane == 0) sbounds[wid] = r;
    }
    __syncthreads();
    const int lo  = sbounds[0];
    const int hi  = sbounds[1];
    const int cnt = hi - lo;

    const f32x4 wg  = reinterpret_cast<const f32x4*>(Wg)[lane];
    const float bgv = bg[0];

    float d = 0.f;
    float ax = 0.f, ay = 0.f, az = 0.f, aw = 0.f;

    int n = lo + (wid << 2);
    for (; n + 3 < hi; n += 4 * NWAVES) {
        const f32x4* rp = reinterpret_cast<const f32x4*>(x + (size_t)n * F) + lane;
        const f32x4 x0 = __builtin_nontemporal_load(rp);
        const f32x4 x1 = __builtin_nontemporal_load(rp + 64);
        const f32x4 x2 = __builtin_nontemporal_load(rp + 128);
        const f32x4 x3 = __builtin_nontemporal_load(rp + 192);

        float p0 = x0.x * wg.x + x0.y * wg.y + x0.z * wg.z + x0.w * wg.w;
        float p1 = x1.x * wg.x + x1.y * wg.y + x1.z * wg.z + x1.w * wg.w;
        float p2 = x2.x * wg.x + x2.y * wg.y + x2.z * wg.z + x2.w * wg.w;
        float p3 = x3.x * wg.x + x3.y * wg.y + x3.z * wg.z + x3.w * wg.w;
        #pragma unroll
        for (int o = 32; o > 0; o >>= 1) {
            p0 += __shfl_xor(p0, o);
            p1 += __shfl_xor(p1, o);
            p2 += __shfl_xor(p2, o);
            p3 += __shfl_xor(p3, o);
        }
        const float e0 = __expf(p0 + bgv);
        const float e1 = __expf(p1 + bgv);
        const float e2 = __expf(p2 + bgv);
        const float e3 = __expf(p3 + bgv);

        const int idx = n - lo;
        if (lane == 0 && idx + 3 < GCAP) {
            glds[idx]     = e0;
            glds[idx + 1] = e1;
            glds[idx + 2] = e2;
            glds[idx + 3] = e3;
        }
        d += (e0 + e1) + (e2 + e3);
        ax += e0 * x0.x + e1 * x1.x + e2 * x2.x + e3 * x3.x;
        ay += e0 * x0.y + e1 * x1.y + e2 * x2.y + e3 * x3.y;
        az += e0 * x0.z + e1 * x1.z + e2 * x2.z + e3 * x3.z;
        aw += e0 * x0.w + e1 * x1.w + e2 * x2.w + e3 * x3.w;
    }
    for (int t = n; t < hi && t < n + 4; ++t) {
        const f32x4 xv = *(reinterpret_cast<const f32x4*>(x + (size_t)t * F) + lane);
        float p = xv.x * wg.x + xv.y * wg.y + xv.z * wg.z + xv.w * wg.w;
        #pragma unroll
        for (int o = 32; o > 0; o >>= 1) p += __shfl_xor(p, o);
        const float e = __expf(p + bgv);
        if (lane == 0 && (t - lo) < GCAP) glds[t - lo] = e;
        d += e;
        ax += e * xv.x; ay += e * xv.y; az += e * xv.z; aw += e * xv.w;
    }

    if (lane == 0) wd[wid] = d;
    f32x4 av = {ax, ay, az, aw};
    reinterpret_cast<f32x4*>(&wacc[wid][0])[lane] = av;
    __syncthreads();

    if (cnt > 0) {
        float D = 0.f;
        #pragma unroll
        for (int w = 0; w < NWAVES; ++w) D += wd[w];
        const float inv = 1.f / (D + 1e-16f);

        if (tid < F) {
            float v = 0.f;
            #pragma unroll
            for (int w = 0; w < NWAVES; ++w) v += wacc[w][tid];
            xbar[tid] = v * inv;
        }

        const int nl = cnt < GCAP ? cnt : GCAP;
        for (int idx = tid; idx < nl; idx += BLOCK) {
            gate_out[lo + idx] = glds[idx] * inv;
        }
        for (int t = lo + GCAP + wid; t < hi; t += NWAVES) {
            const f32x4 xv = *(reinterpret_cast<const f32x4*>(x + (size_t)t * F) + lane);
            float p = xv.x * wg.x + xv.y * wg.y + xv.z * wg.z + xv.w * wg.w;
            #pragma unroll
            for (int o = 32; o > 0; o >>= 1) p += __shfl_xor(p, o);
            if (lane == 0) gate_out[t] = __expf(p + bgv) * inv;
        }
        __syncthreads();

        const int q  = tid >> 8;
        const int j  = tid & 255;
        const int k0 = q * 64;
        float sum = 0.f;
        #pragma unroll 8
        for (int k = k0; k < k0 + 64; ++k) sum += xbar[k] * Wnn[k * F + j];
        partial[tid] = sum;
        __syncthreads();
        if (tid < F) {
            out[(size_t)s * F + tid] = partial[tid] + partial[F + tid] +
                                       partial[2 * F + tid] + partial[3 * F + tid] + bnn[tid];
        }
    } else {
        if (tid < F) out[(size_t)s * F + tid] = 0.f;
    }
}

extern "C" void kernel_launch(void* const* d_in, const int* in_sizes, int n_in,
                              void* d_out, int out_size, void* d_ws, size_t ws_size,
                              hipStream_t stream) {
    const float* x     = (const float*)d_in[0];
    const int*   batch = (const int*)d_in[1];
    const float* Wg    = (const float*)d_in[3];
    const float* bg    = (const float*)d_in[4];
    const float* Wnn   = (const float*)d_in[5];
    const float* bnn   = (const float*)d_in[6];

    float* out  = (float*)d_out;                 // [NGRAPH, F]
    float* gate = out + (size_t)NGRAPH * F;      // [N, 1]
    float* part = (float*)d_ws;

    const int N = in_sizes[0] / F;
    const int chunk = (N + NB - 1) / NB;

    if (ws_size >= (size_t)PART_FLOATS * sizeof(float) && chunk <= BLOCK) {
        void* args[] = {(void*)&x, (void*)&Wg, (void*)&bg, (void*)&Wnn, (void*)&bnn,
                        (void*)&batch, (void*)&N, (void*)&chunk,
                        (void*)&out, (void*)&gate, (void*)&part};
        const hipError_t e = hipLaunchCooperativeKernel(gap_coop, dim3(NB), dim3(BLOCK),
                                                        args, 0u, stream);
        if (e == hipSuccess) return;
        (void)hipGetLastError();   // clear, fall through to monolithic path
    }
    gap_fused<<<NGRAPH, BLOCK, 0, stream>>>(x, Wg, bg, Wnn, bnn, batch, N, out, gate);
}